// Round 5
// baseline (532.135 us; speedup 1.0000x reference)
//
#include <hip/hip_runtime.h>
#include <math.h>

#define BB 64
#define CC 512
#define DTT 1024
#define NNEG 53
#define MARGIN_ 0.2f
#define EPSV 1e-8f
#define KC 32

__device__ __forceinline__ float bred_sum(float v, float* red, int tid, int nt) {
  red[tid] = v; __syncthreads();
  for (int s = nt >> 1; s > 0; s >>= 1) { if (tid < s) red[tid] += red[tid + s]; __syncthreads(); }
  float r = red[0]; __syncthreads();
  return r;
}
__device__ __forceinline__ float bred_max(float v, float* red, int tid, int nt) {
  red[tid] = v; __syncthreads();
  for (int s = nt >> 1; s > 0; s >>= 1) { if (tid < s) red[tid] = fmaxf(red[tid], red[tid + s]); __syncthreads(); }
  float r = red[0]; __syncthreads();
  return r;
}

// K1: sentence centering + l2norm -> Sn (b,c), SnT (c,b), SnSum[b]
__global__ void k_sent(const float* __restrict__ sent, float* __restrict__ Sn,
                       float* __restrict__ SnT, float* __restrict__ SnSum) {
  int b = blockIdx.x, tid = threadIdx.x;
  __shared__ float red[256];
  float x0 = sent[b * CC + tid], x1 = sent[b * CC + tid + 256];
  float mean = bred_sum(x0 + x1, red, tid, 256) * (1.0f / CC);
  float s0 = x0 - mean, s1 = x1 - mean;
  float ss = bred_sum(s0 * s0 + s1 * s1, red, tid, 256);
  float nrm = fmaxf(sqrtf(ss), EPSV);
  float n0 = s0 / nrm, n1 = s1 / nrm;
  Sn[b * CC + tid] = n0; Sn[b * CC + tid + 256] = n1;
  SnT[tid * BB + b] = n0; SnT[(tid + 256) * BB + b] = n1;
  float sn = bred_sum(n0 + n1, red, tid, 256);
  if (tid == 0) SnSum[b] = sn;
}

// KS: sim = Sn Sn^T, stable descending argsort ranks -> nn_idx, negidx, nnsim
__global__ void k_sim(const float* __restrict__ Sn, int* __restrict__ nn_idx,
                      int* __restrict__ negidx, float* __restrict__ nnsim) {
  int i = blockIdx.x, j = threadIdx.x;  // 64 threads
  float dot = 0.f;
  for (int c = 0; c < CC; ++c) dot += Sn[i * CC + c] * Sn[j * CC + c];
  __shared__ float srow[BB];
  srow[j] = dot; __syncthreads();
  float mv = srow[j];
  int rank = 0;
  for (int k = 0; k < BB; ++k) {
    float vk = srow[k];
    if (vk > mv || (vk == mv && k < j)) rank++;
  }
  if (rank == 1) { nn_idx[i] = j; nnsim[i] = mv; }
  if (rank >= 6 && rank < 59) negidx[i * NNEG + rank - 6] = j;
}

// K3: tiled GEMM. Block = (j, 128-wide p chunk); per-thread 8i x 4p micro-tile.
__global__ __launch_bounds__(256) void k_cross(const float* __restrict__ videos,
    const float* __restrict__ SnT, const float* __restrict__ SnSum,
    const float* __restrict__ mask, float* __restrict__ cross,
    float* __restrict__ meanv, float* __restrict__ normv) {
  __shared__ float As[KC][68];    // [c][i], +4 pad
  __shared__ float Bs[KC][132];   // [c][p], +4 pad
  __shared__ float Smb[128], Sinv[128];
  int tid = threadIdx.x;
  int j = blockIdx.x >> 3;
  int p0 = (blockIdx.x & 7) << 7;
  int px = tid & 31;   // 4 p's at p0+px*4
  int iy = tid >> 5;   // 8 i's at iy*8
  int r = tid >> 3;    // staging row 0..31
  int ca = (tid & 7) * 8;
  int cb = (tid & 7) * 16;
  const float* vrow = videos + (size_t)j * CC * DTT + p0 + cb;
  const float* arow0 = SnT + r * BB + ca;

  float acc[8][4];
#pragma unroll
  for (int a = 0; a < 8; ++a)
#pragma unroll
    for (int q = 0; q < 4; ++q) acc[a][q] = 0.f;
  float s4[4] = {0.f, 0.f, 0.f, 0.f}, ss4[4] = {0.f, 0.f, 0.f, 0.f};

  float4 a0 = *(const float4*)(arow0);
  float4 a1 = *(const float4*)(arow0 + 4);
  const float* vr0 = vrow + (size_t)r * DTT;
  float4 b0 = *(const float4*)(vr0);
  float4 b1 = *(const float4*)(vr0 + 4);
  float4 b2 = *(const float4*)(vr0 + 8);
  float4 b3 = *(const float4*)(vr0 + 12);

  for (int kc = 0; kc < CC; kc += KC) {
    *(float4*)&As[r][ca] = a0; *(float4*)&As[r][ca + 4] = a1;
    *(float4*)&Bs[r][cb] = b0; *(float4*)&Bs[r][cb + 4] = b1;
    *(float4*)&Bs[r][cb + 8] = b2; *(float4*)&Bs[r][cb + 12] = b3;
    __syncthreads();
    if (kc + KC < CC) {
      const float* ar = SnT + (size_t)(kc + KC + r) * BB + ca;
      a0 = *(const float4*)(ar); a1 = *(const float4*)(ar + 4);
      const float* vr = vrow + (size_t)(kc + KC + r) * DTT;
      b0 = *(const float4*)(vr); b1 = *(const float4*)(vr + 4);
      b2 = *(const float4*)(vr + 8); b3 = *(const float4*)(vr + 12);
    }
#pragma unroll
    for (int kk = 0; kk < KC; ++kk) {
      float bq[4], ai[8];
      *(float4*)&bq[0] = *(const float4*)&Bs[kk][px * 4];
      *(float4*)&ai[0] = *(const float4*)&As[kk][iy * 8];
      *(float4*)&ai[4] = *(const float4*)&As[kk][iy * 8 + 4];
      if (iy == 0) {
#pragma unroll
        for (int q = 0; q < 4; ++q) { s4[q] += bq[q]; ss4[q] = fmaf(bq[q], bq[q], ss4[q]); }
      }
#pragma unroll
      for (int a = 0; a < 8; ++a)
#pragma unroll
        for (int q = 0; q < 4; ++q)
          acc[a][q] = fmaf(ai[a], bq[q], acc[a][q]);
    }
    __syncthreads();
  }

  if (iy == 0) {
#pragma unroll
    for (int q = 0; q < 4; ++q) {
      float mb = s4[q] * (1.0f / CC);
      float var = ss4[q] - s4[q] * mb;
      float nrm = fmaxf(sqrtf(fmaxf(var, 0.f)), EPSV);
      meanv[j * DTT + p0 + px * 4 + q] = mb;
      normv[j * DTT + p0 + px * 4 + q] = nrm;
      Smb[px * 4 + q] = mb;
      Sinv[px * 4 + q] = 1.f / nrm;
    }
  }
  __syncthreads();
  float mb[4], inv[4], mk[4];
#pragma unroll
  for (int q = 0; q < 4; ++q) {
    mb[q] = Smb[px * 4 + q];
    inv[q] = Sinv[px * 4 + q];
    mk[q] = mask[p0 + px * 4 + q];
  }
#pragma unroll
  for (int a = 0; a < 8; ++a) {
    int i = iy * 8 + a;
    float sni = SnSum[i];
    float4 outv;
    float tmp[4];
#pragma unroll
    for (int q = 0; q < 4; ++q) {
      float val = (acc[a][q] - mb[q] * sni) * inv[q];
      tmp[q] = (mk[q] == 0.f) ? -INFINITY : val;
    }
    outv.x = tmp[0]; outv.y = tmp[1]; outv.z = tmp[2]; outv.w = tmp[3];
    *(float4*)(cross + ((size_t)i * BB + j) * DTT + p0 + px * 4) = outv;
  }
}

// K4: self_score -> pmap out, softmax -> w, wm[b] = sum w*mean
__global__ void k_softmax_w(const float* __restrict__ cross, const float* __restrict__ meanv,
                            float* __restrict__ pmap, float* __restrict__ w, float* __restrict__ wm) {
  int b = blockIdx.x, tid = threadIdx.x;
  __shared__ float red[256];
  const float* row = cross + ((size_t)b * BB + b) * DTT;
  float v[4]; float mx = -INFINITY;
#pragma unroll
  for (int q = 0; q < 4; ++q) {
    v[q] = row[q * 256 + tid];
    pmap[b * DTT + q * 256 + tid] = v[q];
    mx = fmaxf(mx, v[q]);
  }
  mx = bred_max(mx, red, tid, 256);
  float e[4]; float se = 0.f;
#pragma unroll
  for (int q = 0; q < 4; ++q) { e[q] = expf(v[q] - mx); se += e[q]; }
  se = bred_sum(se, red, tid, 256);
  float inv = 1.f / se;
  float wmacc = 0.f;
#pragma unroll
  for (int q = 0; q < 4; ++q) {
    float wv = e[q] * inv;
    w[b * DTT + q * 256 + tid] = wv;
    wmacc += wv * meanv[b * DTT + q * 256 + tid];
  }
  wmacc = bred_sum(wmacc, red, tid, 256);
  if (tid == 0) wm[b] = wmacc;
}

// K5: video_pos[b,c] = sum_p w*videos - wm[b]   (one wave per (b,c))
__global__ void k_vpos(const float* __restrict__ videos, const float* __restrict__ w,
                       const float* __restrict__ wm, float* __restrict__ vp) {
  int wid = (blockIdx.x * 256 + threadIdx.x) >> 6;
  int lane = threadIdx.x & 63;
  int b = wid >> 9, c = wid & 511;
  const float4* vb = (const float4*)(videos + (size_t)(b * CC + c) * DTT) + lane * 4;
  const float4* wb = (const float4*)(w + b * DTT) + lane * 4;
  float acc = 0.f;
#pragma unroll
  for (int q = 0; q < 4; ++q) {
    float4 x = vb[q], y = wb[q];
    acc += x.x * y.x + x.y * y.y + x.z * y.z + x.w * y.w;
  }
#pragma unroll
  for (int off = 32; off > 0; off >>= 1) acc += __shfl_xor(acc, off);
  if (lane == 0) vp[b * CC + c] = acc - wm[b];
}

// Kvpn: ||vp[b]|| and sum_c vp[b,c]
__global__ void k_vpnorm(const float* __restrict__ vp, float* __restrict__ vpn,
                         float* __restrict__ vpsum) {
  int b = blockIdx.x, tid = threadIdx.x;
  __shared__ float red[256];
  float x0 = vp[b * CC + tid], x1 = vp[b * CC + tid + 256];
  float ss = bred_sum(x0 * x0 + x1 * x1, red, tid, 256);
  float sm = bred_sum(x0 + x1, red, tid, 256);
  if (tid == 0) { vpn[b] = fmaxf(sqrtf(ss), EPSV); vpsum[b] = sm; }
}

// K6: vsim logits
__global__ void k_vsim_logits(const float* __restrict__ videos, const float* __restrict__ vp,
    const float* __restrict__ vpn, const float* __restrict__ vpsum, const int* __restrict__ nn_idx,
    const float* __restrict__ meanv, const float* __restrict__ normv, float* __restrict__ vslog) {
  int gid = blockIdx.x * 256 + threadIdx.x;
  int b = gid >> 10, p = gid & 1023;
  int nn = nn_idx[b];
  const float* base = videos + (size_t)nn * CC * DTT + p;
  const float* vpr = vp + b * CC;
  float acc = 0.f;
#pragma unroll 8
  for (int c = 0; c < CC; ++c) acc = fmaf(vpr[c], base[(size_t)c * DTT], acc);
  acc -= meanv[nn * DTT + p] * vpsum[b];
  vslog[gid] = acc / (vpn[b] * normv[nn * DTT + p]);
}

// K7: softmax(vslog) in-place -> vsim ; svp, svn
__global__ void k_softmax_vsim(float* __restrict__ vslog, const int* __restrict__ nn_idx,
    const float* __restrict__ meanv, const float* __restrict__ mask,
    float* __restrict__ svp, float* __restrict__ svn) {
  int b = blockIdx.x, tid = threadIdx.x;
  __shared__ float red[256];
  int nn = nn_idx[b];
  float v[4]; float mx = -INFINITY;
#pragma unroll
  for (int q = 0; q < 4; ++q) { v[q] = vslog[b * DTT + q * 256 + tid]; mx = fmaxf(mx, v[q]); }
  mx = bred_max(mx, red, tid, 256);
  float e[4]; float se = 0.f;
#pragma unroll
  for (int q = 0; q < 4; ++q) { e[q] = expf(v[q] - mx); se += e[q]; }
  se = bred_sum(se, red, tid, 256);
  float inv = 1.f / se;
  float sp = 0.f, sn2 = 0.f;
#pragma unroll
  for (int q = 0; q < 4; ++q) {
    int p = q * 256 + tid;
    float vs = e[q] * inv;
    vslog[b * DTT + p] = vs;
    float mm = meanv[nn * DTT + p];
    sp += vs * mm;
    sn2 += (1.f - vs) * mask[p] * mm;
  }
  sp = bred_sum(sp, red, tid, 256);
  sn2 = bred_sum(sn2, red, tid, 256);
  if (tid == 0) { svp[b] = sp; svn[b] = sn2; }
}

// K8: p_v and n_v  (one wave per (b,c))
__global__ void k_pvnv(const float* __restrict__ videos, const float* __restrict__ vsim,
    const int* __restrict__ nn_idx, const float* __restrict__ mask,
    const float* __restrict__ svp, const float* __restrict__ svn, const int* __restrict__ vn_p,
    float* __restrict__ pv, float* __restrict__ nv) {
  int wid = (blockIdx.x * 256 + threadIdx.x) >> 6;
  int lane = threadIdx.x & 63;
  int b = wid >> 9, c = wid & 511;
  int nn = nn_idx[b];
  const float4* vb = (const float4*)(videos + (size_t)(nn * CC + c) * DTT) + lane * 4;
  const float4* vs4 = (const float4*)(vsim + b * DTT) + lane * 4;
  const float4* m4 = ((const float4*)mask) + lane * 4;
  float ap = 0.f, an = 0.f;
#pragma unroll
  for (int q = 0; q < 4; ++q) {
    float4 x = vb[q], s = vs4[q], m = m4[q];
    ap += x.x * s.x + x.y * s.y + x.z * s.z + x.w * s.w;
    an += x.x * (1.f - s.x) * m.x + x.y * (1.f - s.y) * m.y + x.z * (1.f - s.z) * m.z + x.w * (1.f - s.w) * m.w;
  }
#pragma unroll
  for (int off = 32; off > 0; off >>= 1) { ap += __shfl_xor(ap, off); an += __shfl_xor(an, off); }
  if (lane == 0) {
    float kd = (float)(*vn_p - 1);
    pv[b * CC + c] = ap - svp[b];
    nv[b * CC + c] = (an - svn[b]) / kd;
  }
}

// Kvas: vas per-row mean
__global__ void k_vas(const float* __restrict__ vp, const float* __restrict__ vpn,
                      const float* __restrict__ Sn, const int* __restrict__ negidx,
                      float* __restrict__ vasrow) {
  int i = blockIdx.x, tid = threadIdx.x;  // 64 threads
  __shared__ float red[64];
  __shared__ float pos;
  float invn = 1.f / vpn[i];
  float val = 0.f;
  if (tid < NNEG) {
    int nj = negidx[i * NNEG + tid];
    float d = 0.f;
    for (int c = 0; c < CC; ++c) d += vp[i * CC + c] * Sn[nj * CC + c];
    val = d * invn;
  }
  if (tid == 63) {
    float d = 0.f;
    for (int c = 0; c < CC; ++c) d += vp[i * CC + c] * Sn[i * CC + c];
    pos = d * invn;
  }
  __syncthreads();
  float contrib = (tid < NNEG) ? fmaxf(MARGIN_ + val - pos, 0.f) : 0.f;
  float s = bred_sum(contrib, red, tid, 64);
  if (tid == 0) vasrow[i] = s / (float)NNEG;
}

// Kcrov: crov per-row (gated)
__global__ void k_crov(const float* __restrict__ vp, const float* __restrict__ vpn,
                       const float* __restrict__ pv, const float* __restrict__ nv,
                       const float* __restrict__ nnsim, float* __restrict__ crovrow) {
  int b = blockIdx.x, tid = threadIdx.x;  // 256
  __shared__ float red[256];
  float dp = 0.f, pp = 0.f, dn = 0.f, nn2 = 0.f;
  for (int c = tid; c < CC; c += 256) {
    float a = vp[b * CC + c], x = pv[b * CC + c], y = nv[b * CC + c];
    dp += a * x; pp += x * x; dn += a * y; nn2 += y * y;
  }
  dp = bred_sum(dp, red, tid, 256);
  pp = bred_sum(pp, red, tid, 256);
  dn = bred_sum(dn, red, tid, 256);
  nn2 = bred_sum(nn2, red, tid, 256);
  if (tid == 0) {
    float cosp = dp / (vpn[b] * fmaxf(sqrtf(pp), EPSV));
    float cosn = dn / (vpn[b] * fmaxf(sqrtf(nn2), EPSV));
    float crov = fmaxf(MARGIN_ + cosn - cosp, 0.f);
    crovrow[b] = (nnsim[b] > 0.9f) ? crov : 0.f;
  }
}

// K9: one WAVE per (i,j) row; zero __syncthreads. 4x8-bit radix select on
// 32-bit monotone keys held in registers; shuffle suffix-scan; exact
// jax-stable tie handling; rank-by-count ordering; decay; softmax score.
__global__ __launch_bounds__(256) void k_topk(const float* __restrict__ cross,
    const float* __restrict__ iou, const float* __restrict__ lam_p,
    const int* __restrict__ vn_p, float* __restrict__ scores) {
  __shared__ unsigned int hist_s[4][256];
  __shared__ unsigned int sel_s[4][128];     // selected original index
  __shared__ unsigned int selk_s[4][128];    // selected mono key
  __shared__ unsigned int ordi_s[4][128];    // index, sorted (val desc, idx asc)
  __shared__ float ordv_s[4][128];           // value, sorted
  __shared__ unsigned int cnt_s[4];
  int tid = threadIdx.x;
  int wv = tid >> 6, lane = tid & 63;
  int ij = blockIdx.x * 4 + wv;
  int K = *vn_p; if (K > 128) K = 128;
  float lam = *lam_p;
  unsigned int* hist = hist_s[wv];
  unsigned int* sel = sel_s[wv];
  unsigned int* selk = selk_s[wv];
  unsigned int* ordi = ordi_s[wv];
  float* ordv = ordv_s[wv];

  // load 16 values/lane into registers as monotone u32
  const float* row = cross + (size_t)ij * DTT;
  unsigned int v[16];
#pragma unroll
  for (int q = 0; q < 16; ++q) {
    unsigned u = __float_as_uint(row[q * 64 + lane]);
    v[q] = (u & 0x80000000u) ? ~u : (u | 0x80000000u);
  }
  if (lane == 0) cnt_s[wv] = 0u;
  __builtin_amdgcn_wave_barrier();

  // --- 4x8-bit radix select: threshold T (mono) + #ties to take ---
  unsigned prefix = 0u, pmask = 0u;
  int remaining = K;
  for (int shift = 24; shift >= 0; shift -= 8) {
#pragma unroll
    for (int q = 0; q < 4; ++q) hist[lane * 4 + q] = 0u;
    __builtin_amdgcn_wave_barrier();
#pragma unroll
    for (int q = 0; q < 16; ++q) {
      if ((v[q] & pmask) == prefix)
        atomicAdd(&hist[(v[q] >> shift) & 255u], 1u);
    }
    __builtin_amdgcn_wave_barrier();
    unsigned c0 = hist[lane * 4], c1 = hist[lane * 4 + 1];
    unsigned c2 = hist[lane * 4 + 2], c3 = hist[lane * 4 + 3];
    unsigned s = c0 + c1 + c2 + c3;
    unsigned inc = s;  // suffix-inclusive sum over lanes >= mine (higher bins)
#pragma unroll
    for (int off = 1; off < 64; off <<= 1) {
      unsigned t = __shfl_down(inc, off);
      if (lane + off < 64) inc += t;
    }
    unsigned exc = inc - s;
    bool found = (exc < (unsigned)remaining) && (inc >= (unsigned)remaining);
    unsigned long long bmask = __ballot(found);
    int winner = (int)(__ffsll((unsigned long long)bmask) - 1);
    unsigned packed = 0u;
    if (found) {
      unsigned c = exc;
      unsigned cc[4] = {c0, c1, c2, c3};
      int d = lane * 4;
#pragma unroll
      for (int q = 3; q >= 0; --q) {
        if (c + cc[q] >= (unsigned)remaining) { d = lane * 4 + q; break; }
        c += cc[q];
      }
      packed = ((unsigned)d << 16) | (unsigned)(remaining - (int)c);
    }
    packed = __shfl(packed, winner);
    prefix |= (packed >> 16) << shift;
    remaining = (int)(packed & 0xFFFFu);
    pmask |= 255u << shift;
  }

  // --- compact: all strictly-greater keys (count = K - remaining) ---
#pragma unroll
  for (int q = 0; q < 16; ++q) {
    if (v[q] > prefix) {
      unsigned pos = atomicAdd(&cnt_s[wv], 1u);
      sel[pos] = (unsigned)(q * 64 + lane);
      selk[pos] = v[q];
    }
  }
  __builtin_amdgcn_wave_barrier();
  // --- ties (== T): take 'remaining' smallest indices (jax stable order) ---
  {
    int base = K - remaining;
    int last = -1;
    for (int t = 0; t < remaining; ++t) {
      int mymin = 0x7FFFFFFF;
#pragma unroll
      for (int q = 0; q < 16; ++q) {
        int idx = q * 64 + lane;
        if (v[q] == prefix && idx > last && idx < mymin) mymin = idx;
      }
#pragma unroll
      for (int off = 32; off > 0; off >>= 1) mymin = min(mymin, __shfl_xor(mymin, off));
      if (lane == 0) { sel[base + t] = (unsigned)mymin; selk[base + t] = prefix; }
      last = mymin;
    }
  }
  __builtin_amdgcn_wave_barrier();

  // --- order by rank-count: (mono desc, idx asc); broadcast LDS reads ---
  for (int e = lane; e < K; e += 64) {
    unsigned myidx = sel[e], myk = selk[e];
    int rank = 0;
    for (int m = 0; m < K; ++m) {
      unsigned ok = selk[m];
      rank += (ok > myk || (ok == myk && sel[m] < myidx)) ? 1 : 0;
    }
    ordi[rank] = myidx;
    unsigned u = (myk & 0x80000000u) ? (myk & 0x7FFFFFFFu) : ~myk;
    ordv[rank] = __uint_as_float(u);
  }
  __builtin_amdgcn_wave_barrier();

  // --- decay: lane owns rows r=lane, r=lane+64 ---
  float dkA = 1.f, dkB = 1.f;
  {
    int r = lane;
    if (r < K) {
      const float* irow = iou + (size_t)ordi[r] * DTT;
      int m = 0;
      for (; m + 3 < r; m += 4) {
        float x0 = irow[ordi[m]], x1 = irow[ordi[m + 1]];
        float x2 = irow[ordi[m + 2]], x3 = irow[ordi[m + 3]];
        dkA *= (1.f - x0) * (1.f - x1) * (1.f - x2) * (1.f - x3);
      }
      for (; m < r; ++m) dkA *= (1.f - irow[ordi[m]]);
    }
    r = lane + 64;
    if (r < K) {
      const float* irow = iou + (size_t)ordi[r] * DTT;
      int m = 0;
      for (; m + 3 < r; m += 4) {
        float x0 = irow[ordi[m]], x1 = irow[ordi[m + 1]];
        float x2 = irow[ordi[m + 2]], x3 = irow[ordi[m + 3]];
        dkB *= (1.f - x0) * (1.f - x1) * (1.f - x2) * (1.f - x3);
      }
      for (; m < r; ++m) dkB *= (1.f - irow[ordi[m]]);
    }
  }

  // --- softmax(lam*topv) weighted score (wave shuffle reduce) ---
  bool okA = (lane < K), okB = (lane + 64 < K);
  float vA = okA ? ordv[lane] : 0.f;
  float vB = okB ? ordv[lane + 64] : 0.f;
  float mx = fmaxf(okA ? lam * vA : -INFINITY, okB ? lam * vB : -INFINITY);
#pragma unroll
  for (int off = 32; off > 0; off >>= 1) mx = fmaxf(mx, __shfl_xor(mx, off));
  float eA = okA ? expf(lam * vA - mx) : 0.f;
  float eB = okB ? expf(lam * vB - mx) : 0.f;
  float se = eA + eB;
  float sc = (okA ? eA * dkA * vA : 0.f) + (okB ? eB * dkB * vB : 0.f);
#pragma unroll
  for (int off = 32; off > 0; off >>= 1) {
    se += __shfl_xor(se, off);
    sc += __shfl_xor(sc, off);
  }
  if (lane == 0) scores[ij] = sc / se;
}

// Kfinal: hinge maxima + loss
__global__ void k_final(const float* __restrict__ scores, const float* __restrict__ vasrow,
                        const float* __restrict__ crovrow, float* __restrict__ out) {
  int tid = threadIdx.x;  // 64 threads
  __shared__ float sm[BB * BB];
  __shared__ float red[64];
  for (int q = tid; q < BB * BB; q += 64) sm[q] = scores[q];
  __syncthreads();
  float di = sm[tid * BB + tid];
  float rowmax = 0.f, colmax = 0.f;
  for (int k = 0; k < BB; ++k) {
    if (k != tid) {
      rowmax = fmaxf(rowmax, fmaxf(MARGIN_ + sm[tid * BB + k] - di, 0.f));
      colmax = fmaxf(colmax, fmaxf(MARGIN_ + sm[k * BB + tid] - di, 0.f));
    }
  }
  float total = bred_sum(rowmax + colmax + vasrow[tid] + crovrow[tid], red, tid, 64);
  if (tid == 0) out[0] = total * (1.0f / BB);
}

extern "C" void kernel_launch(void* const* d_in, const int* in_sizes, int n_in,
                              void* d_out, int out_size, void* d_ws, size_t ws_size,
                              hipStream_t stream) {
  const float* videos = (const float*)d_in[0];
  const float* sentences = (const float*)d_in[1];
  const float* lam = (const float*)d_in[2];
  const float* mask = (const float*)d_in[3];
  const int* valid_num = (const int*)d_in[4];
  const float* iou_maps = (const float*)d_in[5];
  float* out = (float*)d_out;
  float* pmap = out + 1;

  float* ws = (float*)d_ws;
  float* Sn = ws;                      // 32768
  float* SnT = Sn + 32768;             // 32768
  float* SnSum = SnT + 32768;          // 64
  float* meanv = SnSum + 64;           // 65536
  float* normv = meanv + 65536;        // 65536
  float* cross = normv + 65536;        // 4194304
  float* w = cross + 4194304;          // 65536
  float* wm = w + 65536;               // 64
  float* vp = wm + 64;                 // 32768
  float* vpn = vp + 32768;             // 64
  float* vpsum = vpn + 64;             // 64
  float* nnsim = vpsum + 64;           // 64
  float* vslog = nnsim + 64;           // 65536 (becomes vsim in-place)
  float* svp = vslog + 65536;          // 64
  float* svn = svp + 64;               // 64
  float* pvb = svn + 64;               // 32768
  float* nvb = pvb + 32768;            // 32768
  float* vasrow = nvb + 32768;         // 64
  float* crovrow = vasrow + 64;        // 64
  float* scores = crovrow + 64;        // 4096
  int* nn_idx = (int*)(scores + 4096); // 64
  int* negidx = nn_idx + 64;           // 3392

  k_sent<<<64, 256, 0, stream>>>(sentences, Sn, SnT, SnSum);
  k_sim<<<64, 64, 0, stream>>>(Sn, nn_idx, negidx, nnsim);
  k_cross<<<512, 256, 0, stream>>>(videos, SnT, SnSum, mask, cross, meanv, normv);
  k_softmax_w<<<64, 256, 0, stream>>>(cross, meanv, pmap, w, wm);
  k_vpos<<<8192, 256, 0, stream>>>(videos, w, wm, vp);
  k_vpnorm<<<64, 256, 0, stream>>>(vp, vpn, vpsum);
  k_vsim_logits<<<256, 256, 0, stream>>>(videos, vp, vpn, vpsum, nn_idx, meanv, normv, vslog);
  k_softmax_vsim<<<64, 256, 0, stream>>>(vslog, nn_idx, meanv, mask, svp, svn);
  k_pvnv<<<8192, 256, 0, stream>>>(videos, vslog, nn_idx, mask, svp, svn, valid_num, pvb, nvb);
  k_vas<<<64, 64, 0, stream>>>(vp, vpn, Sn, negidx, vasrow);
  k_crov<<<64, 256, 0, stream>>>(vp, vpn, pvb, nvb, nnsim, crovrow);
  k_topk<<<1024, 256, 0, stream>>>(cross, iou_maps, lam, valid_num, scores);
  k_final<<<1, 64, 0, stream>>>(scores, vasrow, crovrow, out);
}

// Round 6
// 458.581 us; speedup vs baseline: 1.1604x; 1.1604x over previous
//
#include <hip/hip_runtime.h>
#include <hip/hip_fp16.h>
#include <math.h>

#define BB 64
#define CC 512
#define DTT 1024
#define NNEG 53
#define MARGIN_ 0.2f
#define EPSV 1e-8f
#define KC 32

__device__ __forceinline__ float bred_sum(float v, float* red, int tid, int nt) {
  red[tid] = v; __syncthreads();
  for (int s = nt >> 1; s > 0; s >>= 1) { if (tid < s) red[tid] += red[tid + s]; __syncthreads(); }
  float r = red[0]; __syncthreads();
  return r;
}
__device__ __forceinline__ float bred_max(float v, float* red, int tid, int nt) {
  red[tid] = v; __syncthreads();
  for (int s = nt >> 1; s > 0; s >>= 1) { if (tid < s) red[tid] = fmaxf(red[tid], red[tid + s]); __syncthreads(); }
  float r = red[0]; __syncthreads();
  return r;
}

// K1: sentence centering + l2norm -> Sn (b,c), SnT (c,b), SnSum[b]
__global__ void k_sent(const float* __restrict__ sent, float* __restrict__ Sn,
                       float* __restrict__ SnT, float* __restrict__ SnSum) {
  int b = blockIdx.x, tid = threadIdx.x;
  __shared__ float red[256];
  float x0 = sent[b * CC + tid], x1 = sent[b * CC + tid + 256];
  float mean = bred_sum(x0 + x1, red, tid, 256) * (1.0f / CC);
  float s0 = x0 - mean, s1 = x1 - mean;
  float ss = bred_sum(s0 * s0 + s1 * s1, red, tid, 256);
  float nrm = fmaxf(sqrtf(ss), EPSV);
  float n0 = s0 / nrm, n1 = s1 / nrm;
  Sn[b * CC + tid] = n0; Sn[b * CC + tid + 256] = n1;
  SnT[tid * BB + b] = n0; SnT[(tid + 256) * BB + b] = n1;
  float sn = bred_sum(n0 + n1, red, tid, 256);
  if (tid == 0) SnSum[b] = sn;
}

// KS: sim = Sn Sn^T, stable descending argsort ranks -> nn_idx, negidx, nnsim
__global__ void k_sim(const float* __restrict__ Sn, int* __restrict__ nn_idx,
                      int* __restrict__ negidx, float* __restrict__ nnsim) {
  int i = blockIdx.x, j = threadIdx.x;  // 64 threads
  float dot = 0.f;
  for (int c = 0; c < CC; ++c) dot += Sn[i * CC + c] * Sn[j * CC + c];
  __shared__ float srow[BB];
  srow[j] = dot; __syncthreads();
  float mv = srow[j];
  int rank = 0;
  for (int k = 0; k < BB; ++k) {
    float vk = srow[k];
    if (vk > mv || (vk == mv && k < j)) rank++;
  }
  if (rank == 1) { nn_idx[i] = j; nnsim[i] = mv; }
  if (rank >= 6 && rank < 59) negidx[i * NNEG + rank - 6] = j;
}

// Kprep: L16[p][q] = fp16(1 - iou[p][q])
__global__ void k_prep_iou(const float* __restrict__ iou, __half* __restrict__ L16) {
  int g = (blockIdx.x * 256 + threadIdx.x) * 4;
  float4 x = *(const float4*)(iou + g);
  __half2 h0 = __floats2half2_rn(1.f - x.x, 1.f - x.y);
  __half2 h1 = __floats2half2_rn(1.f - x.z, 1.f - x.w);
  *(__half2*)(L16 + g) = h0;
  *(__half2*)(L16 + g + 2) = h1;
}

// K3: tiled GEMM. Block = (j, 128-wide p chunk); per-thread 8i x 4p micro-tile.
__global__ __launch_bounds__(256) void k_cross(const float* __restrict__ videos,
    const float* __restrict__ SnT, const float* __restrict__ SnSum,
    const float* __restrict__ mask, float* __restrict__ cross,
    float* __restrict__ meanv, float* __restrict__ normv) {
  __shared__ float As[KC][68];    // [c][i], +4 pad
  __shared__ float Bs[KC][132];   // [c][p], +4 pad
  __shared__ float Smb[128], Sinv[128];
  int tid = threadIdx.x;
  int j = blockIdx.x >> 3;
  int p0 = (blockIdx.x & 7) << 7;
  int px = tid & 31;   // 4 p's at p0+px*4
  int iy = tid >> 5;   // 8 i's at iy*8
  int r = tid >> 3;    // staging row 0..31
  int ca = (tid & 7) * 8;
  int cb = (tid & 7) * 16;
  const float* vrow = videos + (size_t)j * CC * DTT + p0 + cb;
  const float* arow0 = SnT + r * BB + ca;

  float acc[8][4];
#pragma unroll
  for (int a = 0; a < 8; ++a)
#pragma unroll
    for (int q = 0; q < 4; ++q) acc[a][q] = 0.f;
  float s4[4] = {0.f, 0.f, 0.f, 0.f}, ss4[4] = {0.f, 0.f, 0.f, 0.f};

  float4 a0 = *(const float4*)(arow0);
  float4 a1 = *(const float4*)(arow0 + 4);
  const float* vr0 = vrow + (size_t)r * DTT;
  float4 b0 = *(const float4*)(vr0);
  float4 b1 = *(const float4*)(vr0 + 4);
  float4 b2 = *(const float4*)(vr0 + 8);
  float4 b3 = *(const float4*)(vr0 + 12);

  for (int kc = 0; kc < CC; kc += KC) {
    *(float4*)&As[r][ca] = a0; *(float4*)&As[r][ca + 4] = a1;
    *(float4*)&Bs[r][cb] = b0; *(float4*)&Bs[r][cb + 4] = b1;
    *(float4*)&Bs[r][cb + 8] = b2; *(float4*)&Bs[r][cb + 12] = b3;
    __syncthreads();
    if (kc + KC < CC) {
      const float* ar = SnT + (size_t)(kc + KC + r) * BB + ca;
      a0 = *(const float4*)(ar); a1 = *(const float4*)(ar + 4);
      const float* vr = vrow + (size_t)(kc + KC + r) * DTT;
      b0 = *(const float4*)(vr); b1 = *(const float4*)(vr + 4);
      b2 = *(const float4*)(vr + 8); b3 = *(const float4*)(vr + 12);
    }
#pragma unroll
    for (int kk = 0; kk < KC; ++kk) {
      float bq[4], ai[8];
      *(float4*)&bq[0] = *(const float4*)&Bs[kk][px * 4];
      *(float4*)&ai[0] = *(const float4*)&As[kk][iy * 8];
      *(float4*)&ai[4] = *(const float4*)&As[kk][iy * 8 + 4];
      if (iy == 0) {
#pragma unroll
        for (int q = 0; q < 4; ++q) { s4[q] += bq[q]; ss4[q] = fmaf(bq[q], bq[q], ss4[q]); }
      }
#pragma unroll
      for (int a = 0; a < 8; ++a)
#pragma unroll
        for (int q = 0; q < 4; ++q)
          acc[a][q] = fmaf(ai[a], bq[q], acc[a][q]);
    }
    __syncthreads();
  }

  if (iy == 0) {
#pragma unroll
    for (int q = 0; q < 4; ++q) {
      float mb = s4[q] * (1.0f / CC);
      float var = ss4[q] - s4[q] * mb;
      float nrm = fmaxf(sqrtf(fmaxf(var, 0.f)), EPSV);
      meanv[j * DTT + p0 + px * 4 + q] = mb;
      normv[j * DTT + p0 + px * 4 + q] = nrm;
      Smb[px * 4 + q] = mb;
      Sinv[px * 4 + q] = 1.f / nrm;
    }
  }
  __syncthreads();
  float mb[4], inv[4], mk[4];
#pragma unroll
  for (int q = 0; q < 4; ++q) {
    mb[q] = Smb[px * 4 + q];
    inv[q] = Sinv[px * 4 + q];
    mk[q] = mask[p0 + px * 4 + q];
  }
#pragma unroll
  for (int a = 0; a < 8; ++a) {
    int i = iy * 8 + a;
    float sni = SnSum[i];
    float4 outv;
    float tmp[4];
#pragma unroll
    for (int q = 0; q < 4; ++q) {
      float val = (acc[a][q] - mb[q] * sni) * inv[q];
      tmp[q] = (mk[q] == 0.f) ? -INFINITY : val;
    }
    outv.x = tmp[0]; outv.y = tmp[1]; outv.z = tmp[2]; outv.w = tmp[3];
    *(float4*)(cross + ((size_t)i * BB + j) * DTT + p0 + px * 4) = outv;
  }
}

// K4: self_score -> pmap out, softmax -> w, wm[b] = sum w*mean
__global__ void k_softmax_w(const float* __restrict__ cross, const float* __restrict__ meanv,
                            float* __restrict__ pmap, float* __restrict__ w, float* __restrict__ wm) {
  int b = blockIdx.x, tid = threadIdx.x;
  __shared__ float red[256];
  const float* row = cross + ((size_t)b * BB + b) * DTT;
  float v[4]; float mx = -INFINITY;
#pragma unroll
  for (int q = 0; q < 4; ++q) {
    v[q] = row[q * 256 + tid];
    pmap[b * DTT + q * 256 + tid] = v[q];
    mx = fmaxf(mx, v[q]);
  }
  mx = bred_max(mx, red, tid, 256);
  float e[4]; float se = 0.f;
#pragma unroll
  for (int q = 0; q < 4; ++q) { e[q] = expf(v[q] - mx); se += e[q]; }
  se = bred_sum(se, red, tid, 256);
  float inv = 1.f / se;
  float wmacc = 0.f;
#pragma unroll
  for (int q = 0; q < 4; ++q) {
    float wv = e[q] * inv;
    w[b * DTT + q * 256 + tid] = wv;
    wmacc += wv * meanv[b * DTT + q * 256 + tid];
  }
  wmacc = bred_sum(wmacc, red, tid, 256);
  if (tid == 0) wm[b] = wmacc;
}

// K5: video_pos[b,c] = sum_p w*videos - wm[b]   (one wave per (b,c))
__global__ void k_vpos(const float* __restrict__ videos, const float* __restrict__ w,
                       const float* __restrict__ wm, float* __restrict__ vp) {
  int wid = (blockIdx.x * 256 + threadIdx.x) >> 6;
  int lane = threadIdx.x & 63;
  int b = wid >> 9, c = wid & 511;
  const float4* vb = (const float4*)(videos + (size_t)(b * CC + c) * DTT) + lane * 4;
  const float4* wb = (const float4*)(w + b * DTT) + lane * 4;
  float acc = 0.f;
#pragma unroll
  for (int q = 0; q < 4; ++q) {
    float4 x = vb[q], y = wb[q];
    acc += x.x * y.x + x.y * y.y + x.z * y.z + x.w * y.w;
  }
#pragma unroll
  for (int off = 32; off > 0; off >>= 1) acc += __shfl_xor(acc, off);
  if (lane == 0) vp[b * CC + c] = acc - wm[b];
}

// Kvpn: ||vp[b]|| and sum_c vp[b,c]
__global__ void k_vpnorm(const float* __restrict__ vp, float* __restrict__ vpn,
                         float* __restrict__ vpsum) {
  int b = blockIdx.x, tid = threadIdx.x;
  __shared__ float red[256];
  float x0 = vp[b * CC + tid], x1 = vp[b * CC + tid + 256];
  float ss = bred_sum(x0 * x0 + x1 * x1, red, tid, 256);
  float sm = bred_sum(x0 + x1, red, tid, 256);
  if (tid == 0) { vpn[b] = fmaxf(sqrtf(ss), EPSV); vpsum[b] = sm; }
}

// K6: vsim logits
__global__ void k_vsim_logits(const float* __restrict__ videos, const float* __restrict__ vp,
    const float* __restrict__ vpn, const float* __restrict__ vpsum, const int* __restrict__ nn_idx,
    const float* __restrict__ meanv, const float* __restrict__ normv, float* __restrict__ vslog) {
  int gid = blockIdx.x * 256 + threadIdx.x;
  int b = gid >> 10, p = gid & 1023;
  int nn = nn_idx[b];
  const float* base = videos + (size_t)nn * CC * DTT + p;
  const float* vpr = vp + b * CC;
  float acc = 0.f;
#pragma unroll 8
  for (int c = 0; c < CC; ++c) acc = fmaf(vpr[c], base[(size_t)c * DTT], acc);
  acc -= meanv[nn * DTT + p] * vpsum[b];
  vslog[gid] = acc / (vpn[b] * normv[nn * DTT + p]);
}

// K7: softmax(vslog) in-place -> vsim ; svp, svn
__global__ void k_softmax_vsim(float* __restrict__ vslog, const int* __restrict__ nn_idx,
    const float* __restrict__ meanv, const float* __restrict__ mask,
    float* __restrict__ svp, float* __restrict__ svn) {
  int b = blockIdx.x, tid = threadIdx.x;
  __shared__ float red[256];
  int nn = nn_idx[b];
  float v[4]; float mx = -INFINITY;
#pragma unroll
  for (int q = 0; q < 4; ++q) { v[q] = vslog[b * DTT + q * 256 + tid]; mx = fmaxf(mx, v[q]); }
  mx = bred_max(mx, red, tid, 256);
  float e[4]; float se = 0.f;
#pragma unroll
  for (int q = 0; q < 4; ++q) { e[q] = expf(v[q] - mx); se += e[q]; }
  se = bred_sum(se, red, tid, 256);
  float inv = 1.f / se;
  float sp = 0.f, sn2 = 0.f;
#pragma unroll
  for (int q = 0; q < 4; ++q) {
    int p = q * 256 + tid;
    float vs = e[q] * inv;
    vslog[b * DTT + p] = vs;
    float mm = meanv[nn * DTT + p];
    sp += vs * mm;
    sn2 += (1.f - vs) * mask[p] * mm;
  }
  sp = bred_sum(sp, red, tid, 256);
  sn2 = bred_sum(sn2, red, tid, 256);
  if (tid == 0) { svp[b] = sp; svn[b] = sn2; }
}

// K8: p_v and n_v  (one wave per (b,c))
__global__ void k_pvnv(const float* __restrict__ videos, const float* __restrict__ vsim,
    const int* __restrict__ nn_idx, const float* __restrict__ mask,
    const float* __restrict__ svp, const float* __restrict__ svn, const int* __restrict__ vn_p,
    float* __restrict__ pv, float* __restrict__ nv) {
  int wid = (blockIdx.x * 256 + threadIdx.x) >> 6;
  int lane = threadIdx.x & 63;
  int b = wid >> 9, c = wid & 511;
  int nn = nn_idx[b];
  const float4* vb = (const float4*)(videos + (size_t)(nn * CC + c) * DTT) + lane * 4;
  const float4* vs4 = (const float4*)(vsim + b * DTT) + lane * 4;
  const float4* m4 = ((const float4*)mask) + lane * 4;
  float ap = 0.f, an = 0.f;
#pragma unroll
  for (int q = 0; q < 4; ++q) {
    float4 x = vb[q], s = vs4[q], m = m4[q];
    ap += x.x * s.x + x.y * s.y + x.z * s.z + x.w * s.w;
    an += x.x * (1.f - s.x) * m.x + x.y * (1.f - s.y) * m.y + x.z * (1.f - s.z) * m.z + x.w * (1.f - s.w) * m.w;
  }
#pragma unroll
  for (int off = 32; off > 0; off >>= 1) { ap += __shfl_xor(ap, off); an += __shfl_xor(an, off); }
  if (lane == 0) {
    float kd = (float)(*vn_p - 1);
    pv[b * CC + c] = ap - svp[b];
    nv[b * CC + c] = (an - svn[b]) / kd;
  }
}

// Kvas: vas per-row mean
__global__ void k_vas(const float* __restrict__ vp, const float* __restrict__ vpn,
                      const float* __restrict__ Sn, const int* __restrict__ negidx,
                      float* __restrict__ vasrow) {
  int i = blockIdx.x, tid = threadIdx.x;  // 64 threads
  __shared__ float red[64];
  __shared__ float pos;
  float invn = 1.f / vpn[i];
  float val = 0.f;
  if (tid < NNEG) {
    int nj = negidx[i * NNEG + tid];
    float d = 0.f;
    for (int c = 0; c < CC; ++c) d += vp[i * CC + c] * Sn[nj * CC + c];
    val = d * invn;
  }
  if (tid == 63) {
    float d = 0.f;
    for (int c = 0; c < CC; ++c) d += vp[i * CC + c] * Sn[i * CC + c];
    pos = d * invn;
  }
  __syncthreads();
  float contrib = (tid < NNEG) ? fmaxf(MARGIN_ + val - pos, 0.f) : 0.f;
  float s = bred_sum(contrib, red, tid, 64);
  if (tid == 0) vasrow[i] = s / (float)NNEG;
}

// Kcrov: crov per-row (gated)
__global__ void k_crov(const float* __restrict__ vp, const float* __restrict__ vpn,
                       const float* __restrict__ pv, const float* __restrict__ nv,
                       const float* __restrict__ nnsim, float* __restrict__ crovrow) {
  int b = blockIdx.x, tid = threadIdx.x;  // 256
  __shared__ float red[256];
  float dp = 0.f, pp = 0.f, dn = 0.f, nn2 = 0.f;
  for (int c = tid; c < CC; c += 256) {
    float a = vp[b * CC + c], x = pv[b * CC + c], y = nv[b * CC + c];
    dp += a * x; pp += x * x; dn += a * y; nn2 += y * y;
  }
  dp = bred_sum(dp, red, tid, 256);
  pp = bred_sum(pp, red, tid, 256);
  dn = bred_sum(dn, red, tid, 256);
  nn2 = bred_sum(nn2, red, tid, 256);
  if (tid == 0) {
    float cosp = dp / (vpn[b] * fmaxf(sqrtf(pp), EPSV));
    float cosn = dn / (vpn[b] * fmaxf(sqrtf(nn2), EPSV));
    float crov = fmaxf(MARGIN_ + cosn - cosp, 0.f);
    crovrow[b] = (nnsim[b] > 0.9f) ? crov : 0.f;
  }
}

// K9a: one WAVE per (i,j) row; radix select + rank order; writes (idx,val) rank-ordered.
__global__ __launch_bounds__(256) void k_select(const float* __restrict__ cross,
    const int* __restrict__ vn_p, unsigned* __restrict__ ordi_g, float* __restrict__ ordv_g) {
  __shared__ unsigned int hist_s[4][256];
  __shared__ unsigned int sel_s[4][128];     // selected original index
  __shared__ unsigned int selk_s[4][128];    // selected mono key
  __shared__ unsigned int cnt_s[4];
  int tid = threadIdx.x;
  int wv = tid >> 6, lane = tid & 63;
  int ij = blockIdx.x * 4 + wv;
  int K = *vn_p; if (K > 128) K = 128;
  unsigned int* hist = hist_s[wv];
  unsigned int* sel = sel_s[wv];
  unsigned int* selk = selk_s[wv];

  const float* row = cross + (size_t)ij * DTT;
  unsigned int v[16];
#pragma unroll
  for (int q = 0; q < 16; ++q) {
    unsigned u = __float_as_uint(row[q * 64 + lane]);
    v[q] = (u & 0x80000000u) ? ~u : (u | 0x80000000u);
  }
  if (lane == 0) cnt_s[wv] = 0u;
  __builtin_amdgcn_wave_barrier();

  unsigned prefix = 0u, pmask = 0u;
  int remaining = K;
  for (int shift = 24; shift >= 0; shift -= 8) {
#pragma unroll
    for (int q = 0; q < 4; ++q) hist[lane * 4 + q] = 0u;
    __builtin_amdgcn_wave_barrier();
#pragma unroll
    for (int q = 0; q < 16; ++q) {
      if ((v[q] & pmask) == prefix)
        atomicAdd(&hist[(v[q] >> shift) & 255u], 1u);
    }
    __builtin_amdgcn_wave_barrier();
    unsigned c0 = hist[lane * 4], c1 = hist[lane * 4 + 1];
    unsigned c2 = hist[lane * 4 + 2], c3 = hist[lane * 4 + 3];
    unsigned s = c0 + c1 + c2 + c3;
    unsigned inc = s;
#pragma unroll
    for (int off = 1; off < 64; off <<= 1) {
      unsigned t = __shfl_down(inc, off);
      if (lane + off < 64) inc += t;
    }
    unsigned exc = inc - s;
    bool found = (exc < (unsigned)remaining) && (inc >= (unsigned)remaining);
    unsigned long long bmask = __ballot(found);
    int winner = (int)(__ffsll((unsigned long long)bmask) - 1);
    unsigned packed = 0u;
    if (found) {
      unsigned c = exc;
      unsigned cc[4] = {c0, c1, c2, c3};
      int d = lane * 4;
#pragma unroll
      for (int q = 3; q >= 0; --q) {
        if (c + cc[q] >= (unsigned)remaining) { d = lane * 4 + q; break; }
        c += cc[q];
      }
      packed = ((unsigned)d << 16) | (unsigned)(remaining - (int)c);
    }
    packed = __shfl(packed, winner);
    prefix |= (packed >> 16) << shift;
    remaining = (int)(packed & 0xFFFFu);
    pmask |= 255u << shift;
  }

#pragma unroll
  for (int q = 0; q < 16; ++q) {
    if (v[q] > prefix) {
      unsigned pos = atomicAdd(&cnt_s[wv], 1u);
      sel[pos] = (unsigned)(q * 64 + lane);
      selk[pos] = v[q];
    }
  }
  __builtin_amdgcn_wave_barrier();
  {
    int base = K - remaining;
    int last = -1;
    for (int t = 0; t < remaining; ++t) {
      int mymin = 0x7FFFFFFF;
#pragma unroll
      for (int q = 0; q < 16; ++q) {
        int idx = q * 64 + lane;
        if (v[q] == prefix && idx > last && idx < mymin) mymin = idx;
      }
#pragma unroll
      for (int off = 32; off > 0; off >>= 1) mymin = min(mymin, __shfl_xor(mymin, off));
      if (lane == 0) { sel[base + t] = (unsigned)mymin; selk[base + t] = prefix; }
      last = mymin;
    }
  }
  __builtin_amdgcn_wave_barrier();

  // rank-by-count: (mono desc, idx asc); write rank-ordered to global
  for (int e = lane; e < K; e += 64) {
    unsigned myidx = sel[e], myk = selk[e];
    int rank = 0;
    for (int m = 0; m < K; ++m) {
      unsigned ok = selk[m];
      rank += (ok > myk || (ok == myk && sel[m] < myidx)) ? 1 : 0;
    }
    unsigned u = (myk & 0x80000000u) ? (myk & 0x7FFFFFFFu) : ~myk;
    ordi_g[ij * 128 + rank] = myidx;
    ordv_g[ij * 128 + rank] = __uint_as_float(u);
  }
}

// K9b: block per (i,j): decay products (wave-per-row, lanes-over-cols, fp16,
// early exit on monotone product) + softmax score.
__global__ __launch_bounds__(256) void k_decay(const __half* __restrict__ L16,
    const unsigned* __restrict__ ordi_g, const float* __restrict__ ordv_g,
    const float* __restrict__ lam_p, const int* __restrict__ vn_p,
    float* __restrict__ scores) {
  __shared__ unsigned ti[128];
  __shared__ float dks[128];
  int ij = blockIdx.x, tid = threadIdx.x;
  int wv = tid >> 6, lane = tid & 63;
  int K = *vn_p; if (K > 128) K = 128;
  float lam = *lam_p;
  if (tid < 128) {
    ti[tid] = (tid < K) ? ordi_g[ij * 128 + tid] : 0u;
    dks[tid] = 1.f;
  }
  __syncthreads();

  for (int r = wv; r < K; r += 4) {
    const __half* irow = L16 + (size_t)ti[r] * DTT;
    float f = 1.f;
    if (lane < r && lane < 64) f = __half2float(irow[ti[lane]]);
    float prod = f;
#pragma unroll
    for (int off = 32; off > 0; off >>= 1) prod *= __shfl_xor(prod, off);
    if (r > 64 && prod > 1e-14f) {
      float f2 = 1.f;
      int m = 64 + lane;
      if (m < r) f2 = __half2float(irow[ti[m]]);
#pragma unroll
      for (int off = 32; off > 0; off >>= 1) f2 *= __shfl_xor(f2, off);
      prod *= f2;
    }
    if (lane == 0) dks[r] = prod;
  }
  __syncthreads();

  if (wv == 0) {
    bool okA = (lane < K), okB = (lane + 64 < K);
    float vA = okA ? ordv_g[ij * 128 + lane] : 0.f;
    float vB = okB ? ordv_g[ij * 128 + lane + 64] : 0.f;
    float mx = fmaxf(okA ? lam * vA : -INFINITY, okB ? lam * vB : -INFINITY);
#pragma unroll
    for (int off = 32; off > 0; off >>= 1) mx = fmaxf(mx, __shfl_xor(mx, off));
    float eA = okA ? expf(lam * vA - mx) : 0.f;
    float eB = okB ? expf(lam * vB - mx) : 0.f;
    float se = eA + eB;
    float sc = (okA ? eA * dks[lane] * vA : 0.f) + (okB ? eB * dks[lane + 64] * vB : 0.f);
#pragma unroll
    for (int off = 32; off > 0; off >>= 1) {
      se += __shfl_xor(se, off);
      sc += __shfl_xor(sc, off);
    }
    if (lane == 0) scores[ij] = sc / se;
  }
}

// Kfinal: hinge maxima + loss
__global__ void k_final(const float* __restrict__ scores, const float* __restrict__ vasrow,
                        const float* __restrict__ crovrow, float* __restrict__ out) {
  int tid = threadIdx.x;  // 64 threads
  __shared__ float sm[BB * BB];
  __shared__ float red[64];
  for (int q = tid; q < BB * BB; q += 64) sm[q] = scores[q];
  __syncthreads();
  float di = sm[tid * BB + tid];
  float rowmax = 0.f, colmax = 0.f;
  for (int k = 0; k < BB; ++k) {
    if (k != tid) {
      rowmax = fmaxf(rowmax, fmaxf(MARGIN_ + sm[tid * BB + k] - di, 0.f));
      colmax = fmaxf(colmax, fmaxf(MARGIN_ + sm[k * BB + tid] - di, 0.f));
    }
  }
  float total = bred_sum(rowmax + colmax + vasrow[tid] + crovrow[tid], red, tid, 64);
  if (tid == 0) out[0] = total * (1.0f / BB);
}

extern "C" void kernel_launch(void* const* d_in, const int* in_sizes, int n_in,
                              void* d_out, int out_size, void* d_ws, size_t ws_size,
                              hipStream_t stream) {
  const float* videos = (const float*)d_in[0];
  const float* sentences = (const float*)d_in[1];
  const float* lam = (const float*)d_in[2];
  const float* mask = (const float*)d_in[3];
  const int* valid_num = (const int*)d_in[4];
  const float* iou_maps = (const float*)d_in[5];
  float* out = (float*)d_out;
  float* pmap = out + 1;

  float* ws = (float*)d_ws;
  float* Sn = ws;                      // 32768
  float* SnT = Sn + 32768;             // 32768
  float* SnSum = SnT + 32768;          // 64
  float* meanv = SnSum + 64;           // 65536
  float* normv = meanv + 65536;        // 65536
  float* cross = normv + 65536;        // 4194304
  float* w = cross + 4194304;          // 65536
  float* wm = w + 65536;               // 64
  float* vp = wm + 64;                 // 32768
  float* vpn = vp + 32768;             // 64
  float* vpsum = vpn + 64;             // 64
  float* nnsim = vpsum + 64;           // 64
  float* vslog = nnsim + 64;           // 65536 (becomes vsim in-place)
  float* svp = vslog + 65536;          // 64
  float* svn = svp + 64;               // 64
  float* pvb = svn + 64;               // 32768
  float* nvb = pvb + 32768;            // 32768
  float* vasrow = nvb + 32768;         // 64
  float* crovrow = vasrow + 64;        // 64
  float* scores = crovrow + 64;        // 4096
  int* nn_idx = (int*)(scores + 4096); // 64
  int* negidx = nn_idx + 64;           // 3392
  unsigned* ordi_g = (unsigned*)(negidx + 3392);   // 524288
  float* ordv_g = (float*)(ordi_g + 524288);       // 524288
  __half* L16 = (__half*)(ordv_g + 524288);        // 1048576 halfs = 2MB

  k_sent<<<64, 256, 0, stream>>>(sentences, Sn, SnT, SnSum);
  k_sim<<<64, 64, 0, stream>>>(Sn, nn_idx, negidx, nnsim);
  k_prep_iou<<<1024, 256, 0, stream>>>(iou_maps, L16);
  k_cross<<<512, 256, 0, stream>>>(videos, SnT, SnSum, mask, cross, meanv, normv);
  k_softmax_w<<<64, 256, 0, stream>>>(cross, meanv, pmap, w, wm);
  k_vpos<<<8192, 256, 0, stream>>>(videos, w, wm, vp);
  k_vpnorm<<<64, 256, 0, stream>>>(vp, vpn, vpsum);
  k_vsim_logits<<<256, 256, 0, stream>>>(videos, vp, vpn, vpsum, nn_idx, meanv, normv, vslog);
  k_softmax_vsim<<<64, 256, 0, stream>>>(vslog, nn_idx, meanv, mask, svp, svn);
  k_pvnv<<<8192, 256, 0, stream>>>(videos, vslog, nn_idx, mask, svp, svn, valid_num, pvb, nvb);
  k_vas<<<64, 64, 0, stream>>>(vp, vpn, Sn, negidx, vasrow);
  k_crov<<<64, 256, 0, stream>>>(vp, vpn, pvb, nvb, nnsim, crovrow);
  k_select<<<1024, 256, 0, stream>>>(cross, valid_num, ordi_g, ordv_g);
  k_decay<<<4096, 256, 0, stream>>>(L16, ordi_g, ordv_g, lam, valid_num, scores);
  k_final<<<1, 64, 0, stream>>>(scores, vasrow, crovrow, out);
}